// Round 15
// baseline (2246.201 us; speedup 1.0000x reference)
//
#include <hip/hip_runtime.h>

// SuperGlue forward. GEMMs + attention via split-bf16 MFMA (hi/lo), flash attention.
// R15: combineK fused into W1 staging — X2 elements read both Opart halves and apply
// the flash merge inline (coeffs cA/cB per (h,n) precomputed per thread; cc&3 == j is
// compile-time). Deletes 18 launches + 144MB msgb round-trip.
// ws layout (floats), 16M + 4096 total:
//   d_a @0, d_b @1M, qb @2M (scT alias), kb @3M, vb @4M, msgb @5M (final mmb only),
//   Opart @6M (2M), Pb/t1 @8M, W1cat @10M (4.5M), bcat @15M, psum/psq/M/L @15M+16K, u/v @16M

#define NPOS 1024
#define DIM  256
#define NLAYER 18

static constexpr float NORMC = -7.6246189861593985f; // -log(2*1024)

typedef float f32x4 __attribute__((ext_vector_type(4)));
typedef unsigned int u32x2 __attribute__((ext_vector_type(2)));
typedef unsigned int u32x4 __attribute__((ext_vector_type(4)));

__device__ __forceinline__ float wredmax(float v){
#pragma unroll
  for (int o = 32; o > 0; o >>= 1) v = fmaxf(v, __shfl_xor(v, o));
  return v;
}
__device__ __forceinline__ float wredsum(float v){
#pragma unroll
  for (int o = 32; o > 0; o >>= 1) v += __shfl_xor(v, o);
  return v;
}

// split fp32 -> bf16 hi (truncate) + bf16 lo (truncate of residual)
__device__ __forceinline__ void cvt2(float x, unsigned short& h, unsigned short& l){
  unsigned xb = __float_as_uint(x);
  h = (unsigned short)(xb >> 16);
  float r = x - __uint_as_float(xb & 0xFFFF0000u);
  l = (unsigned short)(__float_as_uint(r) >> 16);
}
__device__ __forceinline__ u32x2 pack4(const unsigned short* s){
  u32x2 p;
  p.x = (unsigned)s[0] | ((unsigned)s[1] << 16);
  p.y = (unsigned)s[2] | ((unsigned)s[3] << 16);
  return p;
}
__device__ __forceinline__ void mfma_bf16(f32x4& acc, const u32x4& a, const u32x4& b){
  asm volatile("v_mfma_f32_16x16x32_bf16 %0, %1, %2, %0" : "+v"(acc) : "v"(a), "v"(b));
}
// hazard-guarded: s_nop covers VALU<->MFMA wait states around each opaque asm MFMA.
__device__ __forceinline__ void mfma_bf16_hz(f32x4& acc, const u32x4& a, const u32x4& b){
  asm volatile("s_nop 3\n\tv_mfma_f32_16x16x32_bf16 %0, %1, %2, %0" : "+v"(acc) : "v"(a), "v"(b));
}
#define MFMA_FENCE() asm volatile("s_nop 7\n\ts_nop 7\n\ts_nop 7" :::)

// Fragment-order LDS layout for 16x16x32 bf16 MFMA operands:
//  operand subtile = 16 (m|n) x 64 k -> [sub*2+kstep][lane][8 bf16], lane = (i&15) + 16*((k&15)>>2),
//  elem r = ((k>>4)&1)*4 + (k&3)

// ---------------- MFMA GEMM core (prefetched, 64o x 64n tile) ------------------------------
template<bool RESID, bool SPLIT>
__device__ __forceinline__ void gemm_mfma_core(
    const float* __restrict__ W, const float* __restrict__ bias,
    const float* __restrict__ Xb, const float* __restrict__ X2b,
    float* __restrict__ Ob, const float* __restrict__ Rb,
    int K, int o0, int n0)
{
  __shared__ unsigned short lwh[4096], lwl[4096];   // W: 4 o-subs x 2 ks
  __shared__ unsigned short lxh[4096], lxl[4096];   // X: 4 n-subs x 2 ks
  const int t = threadIdx.x;
  const int lane = t & 63, w = t >> 6;
  f32x4 acc[4];
#pragma unroll
  for (int i = 0; i < 4; i++) acc[i] = (f32x4)0.f;

  const int so = t & 63, skq = (t >> 6) << 4;   // W stage: o, k-chunk(16)
  const int sn = t & 63, skg = t >> 6;          // X stage: n, k-group(16)
  const int wmi = so >> 4, wol = so & 15;
  const int wks = skq >> 5, whalf = (skq >> 4) & 1;
  const int xni = sn >> 4, xnl = sn & 15;
  const int xks = skg >> 1, xhalf = skg & 1;

  float4 pw[4];
  float px[16];
  const float* wbase = W + (long)(o0 + so) * K + skq;
  auto loadchunk = [&](int kp) {
#pragma unroll
    for (int q = 0; q < 4; q++) pw[q] = *(const float4*)(wbase + kp + q * 4);
    const float* xr = (SPLIT && kp >= 256) ? (X2b + (long)(kp - 256) * NPOS)
                                           : (Xb + (long)kp * NPOS);
#pragma unroll
    for (int q = 0; q < 4; q++)
#pragma unroll
      for (int j = 0; j < 4; j++)
        px[q * 4 + j] = xr[(long)(skg * 16 + q * 4 + j) * NPOS + n0 + sn];
  };

  loadchunk(0);
  for (int kp = 0; kp < K; kp += 64) {
#pragma unroll
    for (int q = 0; q < 4; q++) {
      unsigned short h[4], l[4];
      cvt2(pw[q].x, h[0], l[0]); cvt2(pw[q].y, h[1], l[1]);
      cvt2(pw[q].z, h[2], l[2]); cvt2(pw[q].w, h[3], l[3]);
      int idx = ((wmi * 2 + wks) * 64 + wol + 16 * q) * 8 + whalf * 4;
      *(u32x2*)&lwh[idx] = pack4(h);
      *(u32x2*)&lwl[idx] = pack4(l);
    }
#pragma unroll
    for (int q = 0; q < 4; q++) {
      unsigned short h[4], l[4];
#pragma unroll
      for (int j = 0; j < 4; j++) cvt2(px[q * 4 + j], h[j], l[j]);
      int idx = ((xni * 2 + xks) * 64 + xnl + 16 * q) * 8 + xhalf * 4;
      *(u32x2*)&lxh[idx] = pack4(h);
      *(u32x2*)&lxl[idx] = pack4(l);
    }
    __syncthreads();
    if (kp + 64 < K) loadchunk(kp + 64);   // latency hides under MFMA
#pragma unroll
    for (int ks = 0; ks < 2; ks++) {
      u32x4 Bh = *(const u32x4*)&lxh[((w * 2 + ks) * 64 + lane) * 8];
      u32x4 Bl = *(const u32x4*)&lxl[((w * 2 + ks) * 64 + lane) * 8];
#pragma unroll
      for (int mi = 0; mi < 4; mi++) {
        u32x4 Ah = *(const u32x4*)&lwh[((mi * 2 + ks) * 64 + lane) * 8];
        u32x4 Al = *(const u32x4*)&lwl[((mi * 2 + ks) * 64 + lane) * 8];
        mfma_bf16(acc[mi], Ah, Bh);
        mfma_bf16(acc[mi], Ah, Bl);
        mfma_bf16(acc[mi], Al, Bh);
      }
    }
    __syncthreads();
  }
  MFMA_FENCE();
  const int l15 = lane & 15, l4 = lane >> 4;
  const int n = n0 + (w << 4) + l15;
#pragma unroll
  for (int mi = 0; mi < 4; mi++) {
#pragma unroll
    for (int r = 0; r < 4; r++) {
      int o = o0 + mi * 16 + l4 * 4 + r;
      float val = acc[mi][r] + bias[o];
      if (RESID) val += Rb[(long)o * NPOS + n];
      Ob[(long)o * NPOS + n] = val;
    }
  }
}

template<bool RESID, bool SPLIT>
__global__ __launch_bounds__(256, 4) void gemm_mfma(
    const float* __restrict__ W, const float* __restrict__ bias,
    const float* __restrict__ X, const float* __restrict__ X2,
    float* __restrict__ out, const float* __restrict__ R,
    int K, long xbs, long x2bs, long obs, long rbs)
{
  const int bz = blockIdx.z;
  gemm_mfma_core<RESID, SPLIT>(W, bias,
      X + (long)bz * xbs, SPLIT ? (X2 + (long)bz * x2bs) : X,
      out + (long)bz * obs, RESID ? (R + (long)bz * rbs) : out,
      K, blockIdx.y * 64, blockIdx.x * 64);
}

__global__ __launch_bounds__(256, 4) void gemm_qkv_mfma(
    const float* __restrict__ Wq, const float* __restrict__ Bq,
    const float* __restrict__ Wk, const float* __restrict__ Bk,
    const float* __restrict__ Wv, const float* __restrict__ Bv,
    const float* __restrict__ X, float* __restrict__ out)
{
  const int z = blockIdx.z;
  const int which = z >> 2, bz = z & 3;
  const float* W    = (which == 0) ? Wq : (which == 1) ? Wk : Wv;
  const float* bias = (which == 0) ? Bq : (which == 1) ? Bk : Bv;
  gemm_mfma_core<false, false>(W, bias,
      X + (long)bz * (DIM * NPOS), nullptr,
      out + (long)which * 1048576 + (long)bz * (DIM * NPOS), nullptr,
      256, blockIdx.y * 64, blockIdx.x * 64);
}

// ---------------- W1 GEMM (split K, 64x64) + fused flash-combine + LN partial stats --------
// X2 rows come from the two Opart halves, merged inline: val = OA*cA[j] + OB*cB[j],
// where cA/cB are per-(h,n) flash-merge coefficients (h = row&3 == j, compile-time).
// psum/psq layout: [oblk(8)][bz(4)][n(1024)]
__global__ __launch_bounds__(256, 4) void gemm_w1s_mfma(
    const float* __restrict__ W, const float* __restrict__ bias,
    const float* __restrict__ X, const float* __restrict__ Op,
    const float* __restrict__ Mp, const float* __restrict__ Lp,
    float* __restrict__ out, float* __restrict__ psum, float* __restrict__ psq)
{
  __shared__ unsigned short lwh[4096], lwl[4096];
  __shared__ unsigned short lxh[4096], lxl[4096];
  const int t = threadIdx.x;
  const int lane = t & 63, w = t >> 6;
  const int bz = blockIdx.z, o0 = blockIdx.y * 64, n0 = blockIdx.x * 64;
  const float* Xb = X + (long)bz * (DIM * NPOS);
  const float* OA = Op + (long)bz * (DIM * NPOS);
  const float* OB = Op + 1048576 + (long)bz * (DIM * NPOS);
  float* Ob = out + (long)bz * (2L * DIM * NPOS);

  const int so = t & 63, skq = (t >> 6) << 4;
  const int sn = t & 63, skg = t >> 6;
  const int wmi = so >> 4, wol = so & 15;
  const int wks = skq >> 5, whalf = (skq >> 4) & 1;
  const int xni = sn >> 4, xnl = sn & 15;
  const int xks = skg >> 1, xhalf = skg & 1;

  // flash-merge coefficients for this thread's column (n0+sn), all 4 heads
  float cA[4], cB[4];
  {
    int n = n0 + sn;
    int gbase = ((bz >> 1) << 3) + ((bz & 1) << 2);
#pragma unroll
    for (int h = 0; h < 4; h++) {
      float ma = Mp[(gbase + h) * 1024 + n];
      float mb2 = Mp[16384 + (gbase + h) * 1024 + n];
      float la = Lp[(gbase + h) * 1024 + n];
      float lb = Lp[16384 + (gbase + h) * 1024 + n];
      float m = fmaxf(ma, mb2);
      float ea = __expf(ma - m), eb = __expf(mb2 - m);
      float inv = 1.f / (la * ea + lb * eb);
      cA[h] = ea * inv; cB[h] = eb * inv;
    }
  }

  f32x4 acc[4];
#pragma unroll
  for (int i = 0; i < 4; i++) acc[i] = (f32x4)0.f;

  float4 pw[4];
  float px[16];
  const float* wbase = W + (long)(o0 + so) * 512 + skq;
  auto loadchunk = [&](int kp) {
#pragma unroll
    for (int q = 0; q < 4; q++) pw[q] = *(const float4*)(wbase + kp + q * 4);
    if (kp >= 256) {
#pragma unroll
      for (int q = 0; q < 4; q++)
#pragma unroll
        for (int j = 0; j < 4; j++) {
          long cc = kp - 256 + skg * 16 + q * 4 + j;
          float xa = OA[cc * NPOS + n0 + sn];
          float xb = OB[cc * NPOS + n0 + sn];
          px[q * 4 + j] = xa * cA[j] + xb * cB[j];   // cc&3 == j
        }
    } else {
#pragma unroll
      for (int q = 0; q < 4; q++)
#pragma unroll
        for (int j = 0; j < 4; j++)
          px[q * 4 + j] = Xb[(long)(kp + skg * 16 + q * 4 + j) * NPOS + n0 + sn];
    }
  };

  loadchunk(0);
  for (int kp = 0; kp < 512; kp += 64) {
#pragma unroll
    for (int q = 0; q < 4; q++) {
      unsigned short h[4], l[4];
      cvt2(pw[q].x, h[0], l[0]); cvt2(pw[q].y, h[1], l[1]);
      cvt2(pw[q].z, h[2], l[2]); cvt2(pw[q].w, h[3], l[3]);
      int idx = ((wmi * 2 + wks) * 64 + wol + 16 * q) * 8 + whalf * 4;
      *(u32x2*)&lwh[idx] = pack4(h);
      *(u32x2*)&lwl[idx] = pack4(l);
    }
#pragma unroll
    for (int q = 0; q < 4; q++) {
      unsigned short h[4], l[4];
#pragma unroll
      for (int j = 0; j < 4; j++) cvt2(px[q * 4 + j], h[j], l[j]);
      int idx = ((xni * 2 + xks) * 64 + xnl + 16 * q) * 8 + xhalf * 4;
      *(u32x2*)&lxh[idx] = pack4(h);
      *(u32x2*)&lxl[idx] = pack4(l);
    }
    __syncthreads();
    if (kp + 64 < 512) loadchunk(kp + 64);
#pragma unroll
    for (int ks = 0; ks < 2; ks++) {
      u32x4 Bh = *(const u32x4*)&lxh[((w * 2 + ks) * 64 + lane) * 8];
      u32x4 Bl = *(const u32x4*)&lxl[((w * 2 + ks) * 64 + lane) * 8];
#pragma unroll
      for (int mi = 0; mi < 4; mi++) {
        u32x4 Ah = *(const u32x4*)&lwh[((mi * 2 + ks) * 64 + lane) * 8];
        u32x4 Al = *(const u32x4*)&lwl[((mi * 2 + ks) * 64 + lane) * 8];
        mfma_bf16(acc[mi], Ah, Bh);
        mfma_bf16(acc[mi], Ah, Bl);
        mfma_bf16(acc[mi], Al, Bh);
      }
    }
    __syncthreads();
  }
  MFMA_FENCE();
  const int l15 = lane & 15, l4 = lane >> 4;
  const int n = n0 + (w << 4) + l15;
  float ps = 0.f, pq = 0.f;
#pragma unroll
  for (int mi = 0; mi < 4; mi++) {
#pragma unroll
    for (int r = 0; r < 4; r++) {
      int o = o0 + mi * 16 + l4 * 4 + r;
      float val = acc[mi][r] + bias[o];
      Ob[(long)o * NPOS + n] = val;
      ps += val; pq += val * val;
    }
  }
  ps += __shfl_xor(ps, 16); ps += __shfl_xor(ps, 32);
  pq += __shfl_xor(pq, 16); pq += __shfl_xor(pq, 32);
  if (l4 == 0) {
    long sidx = ((long)blockIdx.y * 4 + bz) * NPOS + n;
    psum[sidx] = ps;
    psq[sidx]  = pq;
  }
}

// ---------------- W2 GEMM (64x64): X staged with inline LN+ReLU; residual epilogue ---------
__global__ __launch_bounds__(256, 4) void gemm_w2ln_mfma(
    const float* __restrict__ W, const float* __restrict__ bias,
    const float* __restrict__ X, const float* __restrict__ ga, const float* __restrict__ be,
    const float* __restrict__ psum, const float* __restrict__ psq,
    float* __restrict__ out, const float* __restrict__ R)
{
  __shared__ unsigned short lwh[4096], lwl[4096];
  __shared__ unsigned short lxh[4096], lxl[4096];
  __shared__ float meanv[64], invv[64];
  const int t = threadIdx.x;
  const int lane = t & 63, w = t >> 6;
  const int bz = blockIdx.z, o0 = blockIdx.y * 64, n0 = blockIdx.x * 64;
  const float* Xb = X + (long)bz * (2L * DIM * NPOS);
  float* Ob = out + (long)bz * (DIM * NPOS);
  const float* Rb = R + (long)bz * (DIM * NPOS);
  if (t < 64) {
    int n = n0 + t;
    float S = 0.f, S2 = 0.f;
#pragma unroll
    for (int j = 0; j < 8; j++) {
      long sidx = ((long)j * 4 + bz) * NPOS + n;
      S += psum[sidx]; S2 += psq[sidx];
    }
    float mean = S * (1.f / 512.f);
    float var  = (S2 - 512.f * mean * mean) * (1.f / 511.f);
    meanv[t] = mean;
    invv[t]  = 1.f / (sqrtf(fmaxf(var, 0.f)) + 1e-6f);
  }
  __syncthreads();

  f32x4 acc[4];
#pragma unroll
  for (int i = 0; i < 4; i++) acc[i] = (f32x4)0.f;

  const int so = t & 63, skq = (t >> 6) << 4;
  const int sn = t & 63, skg = t >> 6;
  const int wmi = so >> 4, wol = so & 15;
  const int wks = skq >> 5, whalf = (skq >> 4) & 1;
  const int xni = sn >> 4, xnl = sn & 15;
  const int xks = skg >> 1, xhalf = skg & 1;
  const float mn = meanv[sn], iv = invv[sn];

  float4 pw[4];
  float px[16];
  const float* wbase = W + (long)(o0 + so) * 512 + skq;
  auto loadchunk = [&](int kp) {
#pragma unroll
    for (int q = 0; q < 4; q++) pw[q] = *(const float4*)(wbase + kp + q * 4);
#pragma unroll
    for (int q = 0; q < 4; q++)
#pragma unroll
      for (int j = 0; j < 4; j++)
        px[q * 4 + j] = Xb[(long)(kp + skg * 16 + q * 4 + j) * NPOS + n0 + sn];
  };

  loadchunk(0);
  for (int kp = 0; kp < 512; kp += 64) {
#pragma unroll
    for (int q = 0; q < 4; q++) {
      unsigned short h[4], l[4];
      cvt2(pw[q].x, h[0], l[0]); cvt2(pw[q].y, h[1], l[1]);
      cvt2(pw[q].z, h[2], l[2]); cvt2(pw[q].w, h[3], l[3]);
      int idx = ((wmi * 2 + wks) * 64 + wol + 16 * q) * 8 + whalf * 4;
      *(u32x2*)&lwh[idx] = pack4(h);
      *(u32x2*)&lwl[idx] = pack4(l);
    }
#pragma unroll
    for (int q = 0; q < 4; q++) {
      unsigned short h[4], l[4];
#pragma unroll
      for (int j = 0; j < 4; j++) {
        int cc = kp + skg * 16 + q * 4 + j;
        float x = fmaxf((px[q * 4 + j] - mn) * iv * ga[cc] + be[cc], 0.f);
        cvt2(x, h[j], l[j]);
      }
      int idx = ((xni * 2 + xks) * 64 + xnl + 16 * q) * 8 + xhalf * 4;
      *(u32x2*)&lxh[idx] = pack4(h);
      *(u32x2*)&lxl[idx] = pack4(l);
    }
    __syncthreads();
    if (kp + 64 < 512) loadchunk(kp + 64);
#pragma unroll
    for (int ks = 0; ks < 2; ks++) {
      u32x4 Bh = *(const u32x4*)&lxh[((w * 2 + ks) * 64 + lane) * 8];
      u32x4 Bl = *(const u32x4*)&lxl[((w * 2 + ks) * 64 + lane) * 8];
#pragma unroll
      for (int mi = 0; mi < 4; mi++) {
        u32x4 Ah = *(const u32x4*)&lwh[((mi * 2 + ks) * 64 + lane) * 8];
        u32x4 Al = *(const u32x4*)&lwl[((mi * 2 + ks) * 64 + lane) * 8];
        mfma_bf16(acc[mi], Ah, Bh);
        mfma_bf16(acc[mi], Ah, Bl);
        mfma_bf16(acc[mi], Al, Bh);
      }
    }
    __syncthreads();
  }
  MFMA_FENCE();
  const int l15 = lane & 15, l4 = lane >> 4;
  const int n = n0 + (w << 4) + l15;
#pragma unroll
  for (int mi = 0; mi < 4; mi++) {
#pragma unroll
    for (int r = 0; r < 4; r++) {
      int o = o0 + mi * 16 + l4 * 4 + r;
      Ob[(long)o * NPOS + n] = acc[mi][r] + bias[o] + Rb[(long)o * NPOS + n];
    }
  }
}

// ---------------- final score matrices via MFMA (both directions in one launch) ------
__global__ __launch_bounds__(256) void scores_mfma(
    const float* __restrict__ Mm, float* __restrict__ S0, float* __restrict__ S1, float scale)
{
  __shared__ unsigned short lah[4096], lal[4096];
  __shared__ unsigned short lbh[8192], lbl[8192];
  const int t = threadIdx.x, lane = t & 63, w = t >> 6;
  const int m0 = blockIdx.x * 128, n0 = blockIdx.y * 64;
  const int g = blockIdx.z & 1, dir = blockIdx.z >> 1;
  const long BS2 = 2L * DIM * NPOS;
  const float* Ag = (dir ? (Mm + BS2) : Mm) + (long)g * DIM * NPOS;
  const float* Bg = (dir ? Mm : (Mm + BS2)) + (long)g * DIM * NPOS;
  float* Sg = (dir ? S1 : S0) + (long)g * NPOS * NPOS;
  f32x4 acc[4][2];
#pragma unroll
  for (int i = 0; i < 4; i++)
#pragma unroll
    for (int j = 0; j < 2; j++) acc[i][j] = (f32x4)0.f;

  const int an = t & 63, acq = t >> 6;
  const int bm = t & 127, bkg = t >> 7;
  const int ami = an >> 4, anl = an & 15;
  const int aks = acq >> 1, ahalf = acq & 1;
  const int bni = bm >> 4, bnl = bm & 15;

  for (int cp = 0; cp < 256; cp += 64) {
#pragma unroll
    for (int q = 0; q < 4; q++) {
      unsigned short h[4], l[4];
#pragma unroll
      for (int j = 0; j < 4; j++) {
        float x = Ag[(long)(cp + acq * 16 + q * 4 + j) * NPOS + n0 + an];
        cvt2(x, h[j], l[j]);
      }
      int idx = ((ami * 2 + aks) * 64 + anl + 16 * q) * 8 + ahalf * 4;
      *(u32x2*)&lah[idx] = pack4(h);
      *(u32x2*)&lal[idx] = pack4(l);
    }
#pragma unroll
    for (int q = 0; q < 8; q++) {
      unsigned short h[4], l[4];
#pragma unroll
      for (int j = 0; j < 4; j++) {
        float x = Bg[(long)(cp + bkg * 32 + q * 4 + j) * NPOS + m0 + bm];
        cvt2(x, h[j], l[j]);
      }
      int qm = q & 3, half = (q >> 2) & 1;
      int idx = ((bni * 2 + bkg) * 64 + bnl + 16 * qm) * 8 + half * 4;
      *(u32x2*)&lbh[idx] = pack4(h);
      *(u32x2*)&lbl[idx] = pack4(l);
    }
    __syncthreads();
#pragma unroll
    for (int ks = 0; ks < 2; ks++) {
      u32x4 Ah[4], Al[4], Bh[2], Bl[2];
#pragma unroll
      for (int mi = 0; mi < 4; mi++) {
        Ah[mi] = *(const u32x4*)&lah[((mi * 2 + ks) * 64 + lane) * 8];
        Al[mi] = *(const u32x4*)&lal[((mi * 2 + ks) * 64 + lane) * 8];
      }
#pragma unroll
      for (int ni = 0; ni < 2; ni++) {
        int gg = w * 2 + ni;
        Bh[ni] = *(const u32x4*)&lbh[((gg * 2 + ks) * 64 + lane) * 8];
        Bl[ni] = *(const u32x4*)&lbl[((gg * 2 + ks) * 64 + lane) * 8];
      }
#pragma unroll
      for (int mi = 0; mi < 4; mi++)
#pragma unroll
        for (int ni = 0; ni < 2; ni++) {
          mfma_bf16(acc[mi][ni], Ah[mi], Bh[ni]);
          mfma_bf16(acc[mi][ni], Ah[mi], Bl[ni]);
          mfma_bf16(acc[mi][ni], Al[mi], Bh[ni]);
        }
    }
    __syncthreads();
  }
  MFMA_FENCE();
  const int l15 = lane & 15, l4 = lane >> 4;
#pragma unroll
  for (int mi = 0; mi < 4; mi++)
#pragma unroll
    for (int r = 0; r < 4; r++) {
      int n = n0 + mi * 16 + l4 * 4 + r;
#pragma unroll
      for (int ni = 0; ni < 2; ni++) {
        int m = m0 + (w * 2 + ni) * 16 + l15;
        Sg[(long)n * NPOS + m] = acc[mi][ni][r] * scale;
      }
    }
}

// ---------------- partial flash attention: split over m (z=0: tiles 0-7, z=1: 8-15) -------
// Emits unnormalized O_part and per-column (M, L). ML layout: [split(2)][g(16)][n(1024)].
__global__ __launch_bounds__(256) void flash_part(
    const float* __restrict__ Q, const float* __restrict__ K,
    const float* __restrict__ V, float* __restrict__ Op,
    float* __restrict__ Mp, float* __restrict__ Lp, int cross)
{
  __shared__ unsigned short lqh[4096], lql[4096];
  __shared__ unsigned short lkh[4096], lkl[4096];
  __shared__ unsigned short lvh[4096], lvl[4096];
  const int t = threadIdx.x, lane = t & 63, w = t >> 6;
  const int lin = blockIdx.x + 16 * blockIdx.y;
  const int split = blockIdx.z;
  const int xcd = lin & 7, slot = lin >> 3;
  const int g = xcd * 2 + (slot >> 4);
  const int n0 = (slot & 15) * 64;
  const int s = g >> 3, b = (g >> 2) & 1, h = g & 3;
  const int sba = s * 2 + b;
  const int sbb = (cross ? (1 - s) : s) * 2 + b;
  const float* Qg = Q + ((long)sba * DIM + h) * NPOS;
  const float* Kg = K + ((long)sbb * DIM + h) * NPOS;
  const float* Vg = V + ((long)sbb * DIM + h) * NPOS;
  float*       Og = Op + (long)split * 1048576 + ((long)sba * DIM + h) * NPOS;

  // stage Q once (scaled): B-operand layout
  {
    const int n = t & 63;
#pragma unroll
    for (int qq = 0; qq < 4; qq++) {
      int dq = (t >> 6) + qq * 4;
      unsigned short hh[4], ll[4];
#pragma unroll
      for (int j = 0; j < 4; j++) {
        float x = Qg[(long)(4 * (dq * 4 + j)) * NPOS + n0 + n] * 0.125f;
        cvt2(x, hh[j], ll[j]);
      }
      int idx = (((n >> 4) * 2 + (dq >> 3)) * 64 + (n & 15) + 16 * (dq & 3)) * 8 + ((dq >> 2) & 1) * 4;
      *(u32x2*)&lqh[idx] = pack4(hh);
      *(u32x2*)&lql[idx] = pack4(ll);
    }
  }

  float M = -1e30f, L = 0.f;
  f32x4 acc_o[4];
#pragma unroll
  for (int i = 0; i < 4; i++) acc_o[i] = (f32x4)0.f;

  // T14 prefetch: next m-tile's K (16 scalars) + V (4 float4) in registers.
  const int km = t & 63;
  const int vmq = t & 15;
  float pk[16];
  float4 pv4[4];
  auto loadKV = [&](int m0) {
#pragma unroll
    for (int qq = 0; qq < 4; qq++) {
      int dq = (t >> 6) + qq * 4;
#pragma unroll
      for (int j = 0; j < 4; j++)
        pk[qq * 4 + j] = Kg[(long)(4 * (dq * 4 + j)) * NPOS + m0 + km];
    }
#pragma unroll
    for (int pp = 0; pp < 4; pp++) {
      int d = (t >> 4) + pp * 16;
      pv4[pp] = *(const float4*)(Vg + (long)(4 * d) * NPOS + m0 + vmq * 4);
    }
  };

  const int mbase = split * 8;
  loadKV(mbase * 64);
  for (int mt = 0; mt < 8; mt++) {
    __syncthreads();
#pragma unroll
    for (int qq = 0; qq < 4; qq++) {
      int dq = (t >> 6) + qq * 4;
      unsigned short hh[4], ll[4];
#pragma unroll
      for (int j = 0; j < 4; j++) cvt2(pk[qq * 4 + j], hh[j], ll[j]);
      int idx = (((km >> 4) * 2 + (dq >> 3)) * 64 + (km & 15) + 16 * (dq & 3)) * 8 + ((dq >> 2) & 1) * 4;
      *(u32x2*)&lkh[idx] = pack4(hh);
      *(u32x2*)&lkl[idx] = pack4(ll);
    }
#pragma unroll
    for (int pp = 0; pp < 4; pp++) {
      int d = (t >> 4) + pp * 16;
      unsigned short hh[4], ll[4];
      cvt2(pv4[pp].x, hh[0], ll[0]); cvt2(pv4[pp].y, hh[1], ll[1]);
      cvt2(pv4[pp].z, hh[2], ll[2]); cvt2(pv4[pp].w, hh[3], ll[3]);
      int idx = (((d >> 4) * 2 + (vmq >> 3)) * 64 + (d & 15) + 16 * (vmq & 3)) * 8 + ((vmq >> 2) & 1) * 4;
      *(u32x2*)&lvh[idx] = pack4(hh);
      *(u32x2*)&lvl[idx] = pack4(ll);
    }
    __syncthreads();
    if (mt + 1 < 8) loadKV((mbase + mt + 1) * 64);

    // QK^T
    f32x4 s_[4];
#pragma unroll
    for (int ms = 0; ms < 4; ms++) s_[ms] = (f32x4)0.f;
#pragma unroll
    for (int ks = 0; ks < 2; ks++) {
      u32x4 Bh = *(const u32x4*)&lqh[((w * 2 + ks) * 64 + lane) * 8];
      u32x4 Bl = *(const u32x4*)&lql[((w * 2 + ks) * 64 + lane) * 8];
#pragma unroll
      for (int ms = 0; ms < 4; ms++) {
        u32x4 Ah = *(const u32x4*)&lkh[((ms * 2 + ks) * 64 + lane) * 8];
        u32x4 Al = *(const u32x4*)&lkl[((ms * 2 + ks) * 64 + lane) * 8];
        mfma_bf16_hz(s_[ms], Ah, Bh);
        mfma_bf16_hz(s_[ms], Ah, Bl);
        mfma_bf16_hz(s_[ms], Al, Bh);
      }
    }
    MFMA_FENCE();

    // online softmax in registers (lane: n = 16w+(lane&15); 16 m-values)
    float p[4][4];
    float tm = -1e30f;
#pragma unroll
    for (int ms = 0; ms < 4; ms++)
#pragma unroll
      for (int r = 0; r < 4; r++) tm = fmaxf(tm, s_[ms][r]);
    tm = fmaxf(tm, __shfl_xor(tm, 16));
    tm = fmaxf(tm, __shfl_xor(tm, 32));
    float nm = fmaxf(M, tm);
    float fi = __expf(M - nm);
    float rs = 0.f;
#pragma unroll
    for (int ms = 0; ms < 4; ms++)
#pragma unroll
      for (int r = 0; r < 4; r++) {
        float pv = __expf(s_[ms][r] - nm);
        p[ms][r] = pv; rs += pv;
      }
    rs += __shfl_xor(rs, 16);
    rs += __shfl_xor(rs, 32);
    L = L * fi + rs;
    M = nm;

    // pack P into PV B-operands (D-frag is B-layout at same lane)
    u32x4 Bp_h[2], Bp_l[2];
#pragma unroll
    for (int ks = 0; ks < 2; ks++) {
      unsigned short h0[4], l0[4], h1[4], l1[4];
#pragma unroll
      for (int r = 0; r < 4; r++) {
        cvt2(p[2 * ks][r], h0[r], l0[r]);
        cvt2(p[2 * ks + 1][r], h1[r], l1[r]);
      }
      u32x2 a = pack4(h0), bq = pack4(h1);
      Bp_h[ks].x = a.x; Bp_h[ks].y = a.y; Bp_h[ks].z = bq.x; Bp_h[ks].w = bq.y;
      u32x2 c = pack4(l0), dq = pack4(l1);
      Bp_l[ks].x = c.x; Bp_l[ks].y = c.y; Bp_l[ks].z = dq.x; Bp_l[ks].w = dq.y;
    }
#pragma unroll
    for (int ds = 0; ds < 4; ds++)
#pragma unroll
      for (int r = 0; r < 4; r++) acc_o[ds][r] *= fi;

    // PV: O^T[d][n] += V^T · P
#pragma unroll
    for (int ks = 0; ks < 2; ks++)
#pragma unroll
      for (int ds = 0; ds < 4; ds++) {
        u32x4 Ah = *(const u32x4*)&lvh[((ds * 2 + ks) * 64 + lane) * 8];
        u32x4 Al = *(const u32x4*)&lvl[((ds * 2 + ks) * 64 + lane) * 8];
        mfma_bf16_hz(acc_o[ds], Ah, Bp_h[ks]);
        mfma_bf16_hz(acc_o[ds], Ah, Bp_l[ks]);
        mfma_bf16_hz(acc_o[ds], Al, Bp_h[ks]);
      }
    MFMA_FENCE();
  }

  MFMA_FENCE();
  const int nn = n0 + (w << 4) + (lane & 15);
  // unnormalized partial output + per-column stats
#pragma unroll
  for (int ds = 0; ds < 4; ds++)
#pragma unroll
    for (int r = 0; r < 4; r++) {
      int d = ds * 16 + (lane >> 4) * 4 + r;
      Og[(long)(4 * d) * NPOS + nn] = acc_o[ds][r];
    }
  if ((lane >> 4) == 0) {
    Mp[(long)split * 16384 + g * 1024 + nn] = M;
    Lp[(long)split * 16384 + g * 1024 + nn] = L;
  }
}

// ---------------- fold Wm into W1: Wcat = [W1_l | W1_u*Wm], bcat = B1 + W1_u*Bm -------------
__global__ __launch_bounds__(256) void foldW1(
    const float* __restrict__ w1g, const float* __restrict__ mwg,
    const float* __restrict__ b1g, const float* __restrict__ mbg,
    float* __restrict__ Wcat, float* __restrict__ bcat)
{
  const int z = blockIdx.z;
  const float* W1 = w1g + (long)z * 262144;
  const float* Wm = mwg + (long)z * 65536;
  float* out = Wcat + (long)z * 262144;
  const int o0 = blockIdx.y * 64;
  const int t = threadIdx.x;
  if (blockIdx.x >= 4) {
    const int c0 = (int)(blockIdx.x - 4) * 64;
    const int row = t >> 2, cb = (t & 3) * 16;
#pragma unroll
    for (int q = 0; q < 4; q++) {
      *(float4*)(out + (long)(o0 + row) * 512 + c0 + cb + 4 * q) =
          *(const float4*)(W1 + (long)(o0 + row) * 512 + c0 + cb + 4 * q);
    }
    if (blockIdx.x == 4 && t < 64) {
      int o = o0 + t;
      float acc = b1g[z * 512 + o];
      const float* wr = W1 + (long)o * 512 + 256;
      const float* bm = mbg + z * 256;
      for (int j = 0; j < 256; j++) acc += wr[j] * bm[j];
      bcat[z * 512 + o] = acc;
    }
    return;
  }
  __shared__ float As[16][64], Xs[16][64];
  const int c0 = blockIdx.x * 64;
  const int lr = t >> 2, lc = (t & 3) << 2;
  const int xr = t >> 4, xc = (t & 15) << 2;
  const int ty = t >> 4, tx = t & 15;
  float acc[4][4] = {};
  for (int j0 = 0; j0 < 256; j0 += 16) {
    float4 av = *(const float4*)(W1 + (long)(o0 + lr) * 512 + 256 + j0 + lc);
    As[lc + 0][lr] = av.x; As[lc + 1][lr] = av.y; As[lc + 2][lr] = av.z; As[lc + 3][lr] = av.w;
    *(float4*)&Xs[xr][xc] = *(const float4*)(Wm + (long)(j0 + xr) * 256 + c0 + xc);
    __syncthreads();
#pragma unroll
    for (int kk = 0; kk < 16; kk++) {
      float4 a4 = *(const float4*)&As[kk][ty << 2];
      float4 b4 = *(const float4*)&Xs[kk][tx << 2];
      acc[0][0] += a4.x * b4.x; acc[0][1] += a4.x * b4.y; acc[0][2] += a4.x * b4.z; acc[0][3] += a4.x * b4.w;
      acc[1][0] += a4.y * b4.x; acc[1][1] += a4.y * b4.y; acc[1][2] += a4.y * b4.z; acc[1][3] += a4.y * b4.w;
      acc[2][0] += a4.z * b4.x; acc[2][1] += a4.z * b4.y; acc[2][2] += a4.z * b4.z; acc[2][3] += a4.z * b4.w;
      acc[3][0] += a4.w * b4.x; acc[3][1] += a4.w * b4.y; acc[3][2] += a4.w * b4.z; acc[3][3] += a4.w * b4.w;
    }
    __syncthreads();
  }
#pragma unroll
  for (int i = 0; i < 4; i++) {
    float4 v = make_float4(acc[i][0], acc[i][1], acc[i][2], acc[i][3]);
    *(float4*)(out + (long)(o0 + (ty << 2) + i) * 512 + 256 + c0 + (tx << 2)) = v;
  }
}

// ---------------- Sinkhorn half-iteration ----------------
__global__ __launch_bounds__(256) void sinkK(const float* __restrict__ S,
                                             const float* __restrict__ vin,
                                             float* __restrict__ uout, float norm)
{
  const int r = blockIdx.x * 4 + (threadIdx.x >> 6);
  const int lane = threadIdx.x & 63;
  const int b = r >> 10;
  const float* row = S + (long)r * NPOS;
  const float* vv = vin + (b << 10);
  float vals[16]; float mx = -1e30f;
#pragma unroll
  for (int i = 0; i < 16; i++) { vals[i] = row[lane + i * 64] + vv[lane + i * 64]; mx = fmaxf(mx, vals[i]); }
  mx = wredmax(mx);
  float s = 0.f;
#pragma unroll
  for (int i = 0; i < 16; i++) s += __expf(vals[i] - mx);
  s = wredsum(s);
  if (lane == 0) uout[r] = norm - (mx + __logf(s));
}

// ---------------- Z = sc + u + v - norm ----------------
__global__ __launch_bounds__(256) void finZ(float* __restrict__ Z, const float* __restrict__ u,
                                            const float* __restrict__ v, float norm)
{
  long i = (long)blockIdx.x * 256 + threadIdx.x;
  float4 z = ((float4*)Z)[i];
  long e = i << 2;
  int b = (int)(e >> 20); int n = (int)((e >> 10) & 1023); int m = (int)(e & 1023);
  float add = u[(b << 10) + n] - norm;
  const float* vb = v + (b << 10) + m;
  z.x += add + vb[0]; z.y += add + vb[1]; z.z += add + vb[2]; z.w += add + vb[3];
  ((float4*)Z)[i] = z;
}

// ---------------- keypoint encoder (both streams in one launch) ----------
template<int O, int I>
__device__ __forceinline__ void stage_mm(const float* __restrict__ W, const float* __restrict__ bias,
                                         const float* xin, float* xout, int g, int p)
{
  for (int o = g; o < O; o += 4) {
    float acc = bias[o];
    const float* wr = W + o * I;
    for (int i = 0; i < I; i++) acc += wr[i] * xin[i * 64 + p];
    xout[o * 64 + p] = acc;
  }
  __syncthreads();
}
template<int C>
__device__ __forceinline__ void stage_ln(float* x, const float* __restrict__ ga,
                                         const float* __restrict__ be, float* red, int g, int p)
{
  float s = 0.f, s2 = 0.f;
  for (int c = g; c < C; c += 4) { float v = x[c * 64 + p]; s += v; s2 += v * v; }
  red[g * 64 + p] = s; red[(4 + g) * 64 + p] = s2;
  __syncthreads();
  float S  = red[p] + red[64 + p] + red[128 + p] + red[192 + p];
  float S2 = red[256 + p] + red[320 + p] + red[384 + p] + red[448 + p];
  float mean = S / (float)C;
  float var  = (S2 - (float)C * mean * mean) / (float)(C - 1);
  float inv  = 1.f / (sqrtf(fmaxf(var, 0.f)) + 1e-6f);
  __syncthreads();
  for (int c = g; c < C; c += 4) {
    float v = (x[c * 64 + p] - mean) * inv * ga[c] + be[c];
    x[c * 64 + p] = fmaxf(v, 0.f);
  }
  __syncthreads();
}

__global__ __launch_bounds__(256) void kencK(
    const float* __restrict__ kpts0, const float* __restrict__ scr0, const float* __restrict__ desc0,
    const float* __restrict__ kpts1, const float* __restrict__ scr1, const float* __restrict__ desc1,
    const float* __restrict__ w0, const float* __restrict__ b0, const float* __restrict__ g0, const float* __restrict__ be0,
    const float* __restrict__ w1, const float* __restrict__ b1, const float* __restrict__ g1, const float* __restrict__ be1,
    const float* __restrict__ w2, const float* __restrict__ b2, const float* __restrict__ g2, const float* __restrict__ be2,
    const float* __restrict__ w3, const float* __restrict__ b3,
    float* __restrict__ dout)
{
  __shared__ float a0[3 * 64], a1[32 * 64], a2[64 * 64], a3[128 * 64], red[8 * 64];
  const int t = threadIdx.x, p = t & 63, g = t >> 6;
  const int strm = blockIdx.x >> 5;
  const int blk = blockIdx.x & 31;
  const float* kpts = strm ? kpts1 : kpts0;
  const float* scr  = strm ? scr1  : scr0;
  const float* desc = strm ? desc1 : desc0;
  float* dst = dout + (long)strm * 2 * DIM * NPOS;
  const int b = blk >> 4, n0 = (blk & 15) << 6;
  if (g == 0)      a0[p]        = kpts[((b << 10) + n0 + p) * 2];
  else if (g == 1) a0[64 + p]   = kpts[((b << 10) + n0 + p) * 2 + 1];
  else if (g == 2) a0[128 + p]  = scr[(b << 10) + n0 + p];
  __syncthreads();
  stage_mm<32, 3>(w0, b0, a0, a1, g, p);   stage_ln<32>(a1, g0, be0, red, g, p);
  stage_mm<64, 32>(w1, b1, a1, a2, g, p);  stage_ln<64>(a2, g1, be1, red, g, p);
  stage_mm<128, 64>(w2, b2, a2, a3, g, p); stage_ln<128>(a3, g2, be2, red, g, p);
  for (int o = g; o < 256; o += 4) {
    float acc = b3[o];
    const float* wr = w3 + o * 128;
    for (int i = 0; i < 128; i++) acc += wr[i] * a3[i * 64 + p];
    long idx = ((long)(b * 256 + o) << 10) + n0 + p;
    dst[idx] = desc[idx] + acc;
  }
}

// =====================================================================================
extern "C" void kernel_launch(void* const* d_in, const int* in_sizes, int n_in,
                              void* d_out, int out_size, void* d_ws, size_t ws_size,
                              hipStream_t stream)
{
  (void)in_sizes; (void)n_in; (void)out_size; (void)ws_size;
  const float* desc0   = (const float*)d_in[0];
  const float* desc1   = (const float*)d_in[1];
  const float* kpts0   = (const float*)d_in[2];
  const float* kpts1   = (const float*)d_in[3];
  const float* scores0 = (const float*)d_in[4];
  const float* scores1 = (const float*)d_in[5];
  const float* kw0 = (const float*)d_in[6],  *kb0 = (const float*)d_in[7],
             * kg0 = (const float*)d_in[8],  *kbe0 = (const float*)d_in[9];
  const float* kw1 = (const float*)d_in[10], *kb1 = (const float*)d_in[11],
             * kg1 = (const float*)d_in[12], *kbe1 = (const float*)d_in[13];
  const float* kw2 = (const float*)d_in[14], *kb2 = (const float*)d_in[15],
             * kg2 = (const float*)d_in[16], *kbe2 = (const float*)d_in[17];
  const float* kw3 = (const float*)d_in[18], *kb3 = (const float*)d_in[19];
  const float* qw = (const float*)d_in[20], *qbi = (const float*)d_in[21];
  const float* kw = (const float*)d_in[22], *kbi = (const float*)d_in[23];
  const float* vw = (const float*)d_in[24], *vbi = (const float*)d_in[25];
  const float* mw = (const float*)d_in[26], *mbi = (const float*)d_in[27];
  const float* w1g = (const float*)d_in[28], *b1g = (const float*)d_in[29];
  const float* g1g = (const float*)d_in[30], *be1g = (const float*)d_in[31];
  const float* w2g = (const float*)d_in[32], *b2g = (const float*)d_in[33];
  const float* fw = (const float*)d_in[34], *fb = (const float*)d_in[35];

  float* ws = (float*)d_ws;
  const long M1 = 1048576;
  float* d_a  = ws;
  float* d_b  = ws + 1 * M1;
  float* qb   = ws + 2 * M1;
  float* kb   = ws + 3 * M1;
  float* vb   = ws + 4 * M1;
  float* msgb = ws + 5 * M1;            // final-phase mm buffer only
  float* Opart = ws + 6 * M1;           // 2 x 1M partial flash outputs
  float* Pb   = ws + 8 * M1;
  float* t1   = Pb;                     // [4][512][1024], 2M (raw W1 output)
  float* Wcat = ws + 10 * M1;           // 18*512*512 = 4.5M
  float* bcat = ws + 15 * M1;           // 18*512
  float* psum = ws + 15 * M1 + 16384;   // [8][4][1024]
  float* psq  = psum + 32768;           // [8][4][1024]
  float* Mpart = psq + 32768;           // [2][16][1024]
  float* Lpart = Mpart + 32768;         // [2][16][1024]
  float* uu   = ws + 16 * M1;
  float* vv   = uu + 2048;
  float* scT  = qb;                     // alias, final phase
  float* mmb  = msgb;                   // alias, final phase

  foldW1<<<dim3(8, 8, 18), 256, 0, stream>>>(w1g, mw, b1g, mbi, Wcat, bcat);

  kencK<<<64, 256, 0, stream>>>(kpts0, scores0, desc0, kpts1, scores1, desc1,
      kw0, kb0, kg0, kbe0, kw1, kb1, kg1, kbe1, kw2, kb2, kg2, kbe2, kw3, kb3, d_a);

  float* dc = d_a; float* dn = d_b;
  const long BS1 = (long)DIM * NPOS;
  for (int i = 0; i < NLAYER; i++) {
    int cross = i & 1;
    const float* Wq = qw + (long)i * 65536;  const float* Bq = qbi + (long)i * 256;
    const float* Wk = kw + (long)i * 65536;  const float* Bk = kbi + (long)i * 256;
    const float* Wv = vw + (long)i * 65536;  const float* Bv = vbi + (long)i * 256;
    const float* W1 = Wcat + (long)i * 262144; const float* B1 = bcat + (long)i * 512;
    const float* G1 = g1g + (long)i * 512;    const float* BE1 = be1g + (long)i * 512;
    const float* W2 = w2g + (long)i * 131072; const float* B2 = b2g + (long)i * 256;

    gemm_qkv_mfma<<<dim3(16, 4, 12), 256, 0, stream>>>(Wq, Bq, Wk, Bk, Wv, Bv, dc, qb);
    flash_part<<<dim3(16, 16, 2), 256, 0, stream>>>(qb, kb, vb, Opart, Mpart, Lpart, cross);
    gemm_w1s_mfma<<<dim3(16, 8, 4), 256, 0, stream>>>(W1, B1, dc, Opart, Mpart, Lpart,
                                                      t1, psum, psq);
    gemm_w2ln_mfma<<<dim3(16, 4, 4), 256, 0, stream>>>(W2, B2, t1, G1, BE1, psum, psq, dn, dc);
    float* tmp = dc; dc = dn; dn = tmp;
  }

  gemm_mfma<false, false><<<dim3(16, 4, 4), 256, 0, stream>>>(
      fw, fb, dc, nullptr, mmb, nullptr, 256, BS1, 0, BS1, 0);
  float* scf = (float*)d_out;
  scores_mfma<<<dim3(8, 16, 4), 256, 0, stream>>>(mmb, scf, scT, 0.0625f);

  hipMemsetAsync(vv, 0, 2048 * sizeof(float), stream);
  for (int it = 0; it < 100; it++) {
    sinkK<<<512, 256, 0, stream>>>(scf, vv, uu, NORMC);
    sinkK<<<512, 256, 0, stream>>>(scT, uu, vv, NORMC);
  }
  finZ<<<2048, 256, 0, stream>>>(scf, uu, vv, NORMC);
}

// Round 17
// 2239.006 us; speedup vs baseline: 1.0032x; 1.0032x over previous
//
#include <hip/hip_runtime.h>

// SuperGlue forward. GEMMs + attention via split-bf16 MFMA (hi/lo), flash attention.
// R17 = R15 revert (best-known passing state, 2246us). R16's bf16-S sinkhorn FAILED
// numerics (absmax 1.625 > 1.46): 100 log-domain iterations keep the full bf16
// perturbation of S in Z; no headroom for S compression.
// ws layout (floats), 16M + 4096 total:
//   d_a @0, d_b @1M, qb @2M (scT alias), kb @3M, vb @4M, msgb @5M (final mmb only),
//   Opart @6M (2M), Pb/t1 @8M, W1cat @10M (4.5M), bcat @15M, psum/psq/M/L @15M+16K, u/v @16M

#define NPOS 1024
#define DIM  256
#define NLAYER 18

static constexpr float NORMC = -7.6246189861593985f; // -log(2*1024)

typedef float f32x4 __attribute__((ext_vector_type(4)));
typedef unsigned int u32x2 __attribute__((ext_vector_type(2)));
typedef unsigned int u32x4 __attribute__((ext_vector_type(4)));

__device__ __forceinline__ float wredmax(float v){
#pragma unroll
  for (int o = 32; o > 0; o >>= 1) v = fmaxf(v, __shfl_xor(v, o));
  return v;
}
__device__ __forceinline__ float wredsum(float v){
#pragma unroll
  for (int o = 32; o > 0; o >>= 1) v += __shfl_xor(v, o);
  return v;
}

// split fp32 -> bf16 hi (truncate) + bf16 lo (truncate of residual)
__device__ __forceinline__ void cvt2(float x, unsigned short& h, unsigned short& l){
  unsigned xb = __float_as_uint(x);
  h = (unsigned short)(xb >> 16);
  float r = x - __uint_as_float(xb & 0xFFFF0000u);
  l = (unsigned short)(__float_as_uint(r) >> 16);
}
__device__ __forceinline__ u32x2 pack4(const unsigned short* s){
  u32x2 p;
  p.x = (unsigned)s[0] | ((unsigned)s[1] << 16);
  p.y = (unsigned)s[2] | ((unsigned)s[3] << 16);
  return p;
}
__device__ __forceinline__ void mfma_bf16(f32x4& acc, const u32x4& a, const u32x4& b){
  asm volatile("v_mfma_f32_16x16x32_bf16 %0, %1, %2, %0" : "+v"(acc) : "v"(a), "v"(b));
}
// hazard-guarded: s_nop covers VALU<->MFMA wait states around each opaque asm MFMA.
__device__ __forceinline__ void mfma_bf16_hz(f32x4& acc, const u32x4& a, const u32x4& b){
  asm volatile("s_nop 3\n\tv_mfma_f32_16x16x32_bf16 %0, %1, %2, %0" : "+v"(acc) : "v"(a), "v"(b));
}
#define MFMA_FENCE() asm volatile("s_nop 7\n\ts_nop 7\n\ts_nop 7" :::)

// Fragment-order LDS layout for 16x16x32 bf16 MFMA operands:
//  operand subtile = 16 (m|n) x 64 k -> [sub*2+kstep][lane][8 bf16], lane = (i&15) + 16*((k&15)>>2),
//  elem r = ((k>>4)&1)*4 + (k&3)

// ---------------- MFMA GEMM core (prefetched, 64o x 64n tile) ------------------------------
template<bool RESID, bool SPLIT>
__device__ __forceinline__ void gemm_mfma_core(
    const float* __restrict__ W, const float* __restrict__ bias,
    const float* __restrict__ Xb, const float* __restrict__ X2b,
    float* __restrict__ Ob, const float* __restrict__ Rb,
    int K, int o0, int n0)
{
  __shared__ unsigned short lwh[4096], lwl[4096];   // W: 4 o-subs x 2 ks
  __shared__ unsigned short lxh[4096], lxl[4096];   // X: 4 n-subs x 2 ks
  const int t = threadIdx.x;
  const int lane = t & 63, w = t >> 6;
  f32x4 acc[4];
#pragma unroll
  for (int i = 0; i < 4; i++) acc[i] = (f32x4)0.f;

  const int so = t & 63, skq = (t >> 6) << 4;   // W stage: o, k-chunk(16)
  const int sn = t & 63, skg = t >> 6;          // X stage: n, k-group(16)
  const int wmi = so >> 4, wol = so & 15;
  const int wks = skq >> 5, whalf = (skq >> 4) & 1;
  const int xni = sn >> 4, xnl = sn & 15;
  const int xks = skg >> 1, xhalf = skg & 1;

  float4 pw[4];
  float px[16];
  const float* wbase = W + (long)(o0 + so) * K + skq;
  auto loadchunk = [&](int kp) {
#pragma unroll
    for (int q = 0; q < 4; q++) pw[q] = *(const float4*)(wbase + kp + q * 4);
    const float* xr = (SPLIT && kp >= 256) ? (X2b + (long)(kp - 256) * NPOS)
                                           : (Xb + (long)kp * NPOS);
#pragma unroll
    for (int q = 0; q < 4; q++)
#pragma unroll
      for (int j = 0; j < 4; j++)
        px[q * 4 + j] = xr[(long)(skg * 16 + q * 4 + j) * NPOS + n0 + sn];
  };

  loadchunk(0);
  for (int kp = 0; kp < K; kp += 64) {
#pragma unroll
    for (int q = 0; q < 4; q++) {
      unsigned short h[4], l[4];
      cvt2(pw[q].x, h[0], l[0]); cvt2(pw[q].y, h[1], l[1]);
      cvt2(pw[q].z, h[2], l[2]); cvt2(pw[q].w, h[3], l[3]);
      int idx = ((wmi * 2 + wks) * 64 + wol + 16 * q) * 8 + whalf * 4;
      *(u32x2*)&lwh[idx] = pack4(h);
      *(u32x2*)&lwl[idx] = pack4(l);
    }
#pragma unroll
    for (int q = 0; q < 4; q++) {
      unsigned short h[4], l[4];
#pragma unroll
      for (int j = 0; j < 4; j++) cvt2(px[q * 4 + j], h[j], l[j]);
      int idx = ((xni * 2 + xks) * 64 + xnl + 16 * q) * 8 + xhalf * 4;
      *(u32x2*)&lxh[idx] = pack4(h);
      *(u32x2*)&lxl[idx] = pack4(l);
    }
    __syncthreads();
    if (kp + 64 < K) loadchunk(kp + 64);   // latency hides under MFMA
#pragma unroll
    for (int ks = 0; ks < 2; ks++) {
      u32x4 Bh = *(const u32x4*)&lxh[((w * 2 + ks) * 64 + lane) * 8];
      u32x4 Bl = *(const u32x4*)&lxl[((w * 2 + ks) * 64 + lane) * 8];
#pragma unroll
      for (int mi = 0; mi < 4; mi++) {
        u32x4 Ah = *(const u32x4*)&lwh[((mi * 2 + ks) * 64 + lane) * 8];
        u32x4 Al = *(const u32x4*)&lwl[((mi * 2 + ks) * 64 + lane) * 8];
        mfma_bf16(acc[mi], Ah, Bh);
        mfma_bf16(acc[mi], Ah, Bl);
        mfma_bf16(acc[mi], Al, Bh);
      }
    }
    __syncthreads();
  }
  MFMA_FENCE();
  const int l15 = lane & 15, l4 = lane >> 4;
  const int n = n0 + (w << 4) + l15;
#pragma unroll
  for (int mi = 0; mi < 4; mi++) {
#pragma unroll
    for (int r = 0; r < 4; r++) {
      int o = o0 + mi * 16 + l4 * 4 + r;
      float val = acc[mi][r] + bias[o];
      if (RESID) val += Rb[(long)o * NPOS + n];
      Ob[(long)o * NPOS + n] = val;
    }
  }
}

template<bool RESID, bool SPLIT>
__global__ __launch_bounds__(256, 4) void gemm_mfma(
    const float* __restrict__ W, const float* __restrict__ bias,
    const float* __restrict__ X, const float* __restrict__ X2,
    float* __restrict__ out, const float* __restrict__ R,
    int K, long xbs, long x2bs, long obs, long rbs)
{
  const int bz = blockIdx.z;
  gemm_mfma_core<RESID, SPLIT>(W, bias,
      X + (long)bz * xbs, SPLIT ? (X2 + (long)bz * x2bs) : X,
      out + (long)bz * obs, RESID ? (R + (long)bz * rbs) : out,
      K, blockIdx.y * 64, blockIdx.x * 64);
}

__global__ __launch_bounds__(256, 4) void gemm_qkv_mfma(
    const float* __restrict__ Wq, const float* __restrict__ Bq,
    const float* __restrict__ Wk, const float* __restrict__ Bk,
    const float* __restrict__ Wv, const float* __restrict__ Bv,
    const float* __restrict__ X, float* __restrict__ out)
{
  const int z = blockIdx.z;
  const int which = z >> 2, bz = z & 3;
  const float* W    = (which == 0) ? Wq : (which == 1) ? Wk : Wv;
  const float* bias = (which == 0) ? Bq : (which == 1) ? Bk : Bv;
  gemm_mfma_core<false, false>(W, bias,
      X + (long)bz * (DIM * NPOS), nullptr,
      out + (long)which * 1048576 + (long)bz * (DIM * NPOS), nullptr,
      256, blockIdx.y * 64, blockIdx.x * 64);
}

// ---------------- W1 GEMM (split K, 64x64) + fused flash-combine + LN partial stats --------
// X2 rows come from the two Opart halves, merged inline: val = OA*cA[j] + OB*cB[j],
// where cA/cB are per-(h,n) flash-merge coefficients (h = row&3 == j, compile-time).
// psum/psq layout: [oblk(8)][bz(4)][n(1024)]
__global__ __launch_bounds__(256, 4) void gemm_w1s_mfma(
    const float* __restrict__ W, const float* __restrict__ bias,
    const float* __restrict__ X, const float* __restrict__ Op,
    const float* __restrict__ Mp, const float* __restrict__ Lp,
    float* __restrict__ out, float* __restrict__ psum, float* __restrict__ psq)
{
  __shared__ unsigned short lwh[4096], lwl[4096];
  __shared__ unsigned short lxh[4096], lxl[4096];
  const int t = threadIdx.x;
  const int lane = t & 63, w = t >> 6;
  const int bz = blockIdx.z, o0 = blockIdx.y * 64, n0 = blockIdx.x * 64;
  const float* Xb = X + (long)bz * (DIM * NPOS);
  const float* OA = Op + (long)bz * (DIM * NPOS);
  const float* OB = Op + 1048576 + (long)bz * (DIM * NPOS);
  float* Ob = out + (long)bz * (2L * DIM * NPOS);

  const int so = t & 63, skq = (t >> 6) << 4;
  const int sn = t & 63, skg = t >> 6;
  const int wmi = so >> 4, wol = so & 15;
  const int wks = skq >> 5, whalf = (skq >> 4) & 1;
  const int xni = sn >> 4, xnl = sn & 15;
  const int xks = skg >> 1, xhalf = skg & 1;

  // flash-merge coefficients for this thread's column (n0+sn), all 4 heads
  float cA[4], cB[4];
  {
    int n = n0 + sn;
    int gbase = ((bz >> 1) << 3) + ((bz & 1) << 2);
#pragma unroll
    for (int h = 0; h < 4; h++) {
      float ma = Mp[(gbase + h) * 1024 + n];
      float mb2 = Mp[16384 + (gbase + h) * 1024 + n];
      float la = Lp[(gbase + h) * 1024 + n];
      float lb = Lp[16384 + (gbase + h) * 1024 + n];
      float m = fmaxf(ma, mb2);
      float ea = __expf(ma - m), eb = __expf(mb2 - m);
      float inv = 1.f / (la * ea + lb * eb);
      cA[h] = ea * inv; cB[h] = eb * inv;
    }
  }

  f32x4 acc[4];
#pragma unroll
  for (int i = 0; i < 4; i++) acc[i] = (f32x4)0.f;

  float4 pw[4];
  float px[16];
  const float* wbase = W + (long)(o0 + so) * 512 + skq;
  auto loadchunk = [&](int kp) {
#pragma unroll
    for (int q = 0; q < 4; q++) pw[q] = *(const float4*)(wbase + kp + q * 4);
    if (kp >= 256) {
#pragma unroll
      for (int q = 0; q < 4; q++)
#pragma unroll
        for (int j = 0; j < 4; j++) {
          long cc = kp - 256 + skg * 16 + q * 4 + j;
          float xa = OA[cc * NPOS + n0 + sn];
          float xb = OB[cc * NPOS + n0 + sn];
          px[q * 4 + j] = xa * cA[j] + xb * cB[j];   // cc&3 == j
        }
    } else {
#pragma unroll
      for (int q = 0; q < 4; q++)
#pragma unroll
        for (int j = 0; j < 4; j++)
          px[q * 4 + j] = Xb[(long)(kp + skg * 16 + q * 4 + j) * NPOS + n0 + sn];
    }
  };

  loadchunk(0);
  for (int kp = 0; kp < 512; kp += 64) {
#pragma unroll
    for (int q = 0; q < 4; q++) {
      unsigned short h[4], l[4];
      cvt2(pw[q].x, h[0], l[0]); cvt2(pw[q].y, h[1], l[1]);
      cvt2(pw[q].z, h[2], l[2]); cvt2(pw[q].w, h[3], l[3]);
      int idx = ((wmi * 2 + wks) * 64 + wol + 16 * q) * 8 + whalf * 4;
      *(u32x2*)&lwh[idx] = pack4(h);
      *(u32x2*)&lwl[idx] = pack4(l);
    }
#pragma unroll
    for (int q = 0; q < 4; q++) {
      unsigned short h[4], l[4];
#pragma unroll
      for (int j = 0; j < 4; j++) cvt2(px[q * 4 + j], h[j], l[j]);
      int idx = ((xni * 2 + xks) * 64 + xnl + 16 * q) * 8 + xhalf * 4;
      *(u32x2*)&lxh[idx] = pack4(h);
      *(u32x2*)&lxl[idx] = pack4(l);
    }
    __syncthreads();
    if (kp + 64 < 512) loadchunk(kp + 64);
#pragma unroll
    for (int ks = 0; ks < 2; ks++) {
      u32x4 Bh = *(const u32x4*)&lxh[((w * 2 + ks) * 64 + lane) * 8];
      u32x4 Bl = *(const u32x4*)&lxl[((w * 2 + ks) * 64 + lane) * 8];
#pragma unroll
      for (int mi = 0; mi < 4; mi++) {
        u32x4 Ah = *(const u32x4*)&lwh[((mi * 2 + ks) * 64 + lane) * 8];
        u32x4 Al = *(const u32x4*)&lwl[((mi * 2 + ks) * 64 + lane) * 8];
        mfma_bf16(acc[mi], Ah, Bh);
        mfma_bf16(acc[mi], Ah, Bl);
        mfma_bf16(acc[mi], Al, Bh);
      }
    }
    __syncthreads();
  }
  MFMA_FENCE();
  const int l15 = lane & 15, l4 = lane >> 4;
  const int n = n0 + (w << 4) + l15;
  float ps = 0.f, pq = 0.f;
#pragma unroll
  for (int mi = 0; mi < 4; mi++) {
#pragma unroll
    for (int r = 0; r < 4; r++) {
      int o = o0 + mi * 16 + l4 * 4 + r;
      float val = acc[mi][r] + bias[o];
      Ob[(long)o * NPOS + n] = val;
      ps += val; pq += val * val;
    }
  }
  ps += __shfl_xor(ps, 16); ps += __shfl_xor(ps, 32);
  pq += __shfl_xor(pq, 16); pq += __shfl_xor(pq, 32);
  if (l4 == 0) {
    long sidx = ((long)blockIdx.y * 4 + bz) * NPOS + n;
    psum[sidx] = ps;
    psq[sidx]  = pq;
  }
}

// ---------------- W2 GEMM (64x64): X staged with inline LN+ReLU; residual epilogue ---------
__global__ __launch_bounds__(256, 4) void gemm_w2ln_mfma(
    const float* __restrict__ W, const float* __restrict__ bias,
    const float* __restrict__ X, const float* __restrict__ ga, const float* __restrict__ be,
    const float* __restrict__ psum, const float* __restrict__ psq,
    float* __restrict__ out, const float* __restrict__ R)
{
  __shared__ unsigned short lwh[4096], lwl[4096];
  __shared__ unsigned short lxh[4096], lxl[4096];
  __shared__ float meanv[64], invv[64];
  const int t = threadIdx.x;
  const int lane = t & 63, w = t >> 6;
  const int bz = blockIdx.z, o0 = blockIdx.y * 64, n0 = blockIdx.x * 64;
  const float* Xb = X + (long)bz * (2L * DIM * NPOS);
  float* Ob = out + (long)bz * (DIM * NPOS);
  const float* Rb = R + (long)bz * (DIM * NPOS);
  if (t < 64) {
    int n = n0 + t;
    float S = 0.f, S2 = 0.f;
#pragma unroll
    for (int j = 0; j < 8; j++) {
      long sidx = ((long)j * 4 + bz) * NPOS + n;
      S += psum[sidx]; S2 += psq[sidx];
    }
    float mean = S * (1.f / 512.f);
    float var  = (S2 - 512.f * mean * mean) * (1.f / 511.f);
    meanv[t] = mean;
    invv[t]  = 1.f / (sqrtf(fmaxf(var, 0.f)) + 1e-6f);
  }
  __syncthreads();

  f32x4 acc[4];
#pragma unroll
  for (int i = 0; i < 4; i++) acc[i] = (f32x4)0.f;

  const int so = t & 63, skq = (t >> 6) << 4;
  const int sn = t & 63, skg = t >> 6;
  const int wmi = so >> 4, wol = so & 15;
  const int wks = skq >> 5, whalf = (skq >> 4) & 1;
  const int xni = sn >> 4, xnl = sn & 15;
  const int xks = skg >> 1, xhalf = skg & 1;
  const float mn = meanv[sn], iv = invv[sn];

  float4 pw[4];
  float px[16];
  const float* wbase = W + (long)(o0 + so) * 512 + skq;
  auto loadchunk = [&](int kp) {
#pragma unroll
    for (int q = 0; q < 4; q++) pw[q] = *(const float4*)(wbase + kp + q * 4);
#pragma unroll
    for (int q = 0; q < 4; q++)
#pragma unroll
      for (int j = 0; j < 4; j++)
        px[q * 4 + j] = Xb[(long)(kp + skg * 16 + q * 4 + j) * NPOS + n0 + sn];
  };

  loadchunk(0);
  for (int kp = 0; kp < 512; kp += 64) {
#pragma unroll
    for (int q = 0; q < 4; q++) {
      unsigned short h[4], l[4];
      cvt2(pw[q].x, h[0], l[0]); cvt2(pw[q].y, h[1], l[1]);
      cvt2(pw[q].z, h[2], l[2]); cvt2(pw[q].w, h[3], l[3]);
      int idx = ((wmi * 2 + wks) * 64 + wol + 16 * q) * 8 + whalf * 4;
      *(u32x2*)&lwh[idx] = pack4(h);
      *(u32x2*)&lwl[idx] = pack4(l);
    }
#pragma unroll
    for (int q = 0; q < 4; q++) {
      unsigned short h[4], l[4];
#pragma unroll
      for (int j = 0; j < 4; j++) {
        int cc = kp + skg * 16 + q * 4 + j;
        float x = fmaxf((px[q * 4 + j] - mn) * iv * ga[cc] + be[cc], 0.f);
        cvt2(x, h[j], l[j]);
      }
      int idx = ((xni * 2 + xks) * 64 + xnl + 16 * q) * 8 + xhalf * 4;
      *(u32x2*)&lxh[idx] = pack4(h);
      *(u32x2*)&lxl[idx] = pack4(l);
    }
    __syncthreads();
    if (kp + 64 < 512) loadchunk(kp + 64);
#pragma unroll
    for (int ks = 0; ks < 2; ks++) {
      u32x4 Bh = *(const u32x4*)&lxh[((w * 2 + ks) * 64 + lane) * 8];
      u32x4 Bl = *(const u32x4*)&lxl[((w * 2 + ks) * 64 + lane) * 8];
#pragma unroll
      for (int mi = 0; mi < 4; mi++) {
        u32x4 Ah = *(const u32x4*)&lwh[((mi * 2 + ks) * 64 + lane) * 8];
        u32x4 Al = *(const u32x4*)&lwl[((mi * 2 + ks) * 64 + lane) * 8];
        mfma_bf16(acc[mi], Ah, Bh);
        mfma_bf16(acc[mi], Ah, Bl);
        mfma_bf16(acc[mi], Al, Bh);
      }
    }
    __syncthreads();
  }
  MFMA_FENCE();
  const int l15 = lane & 15, l4 = lane >> 4;
  const int n = n0 + (w << 4) + l15;
#pragma unroll
  for (int mi = 0; mi < 4; mi++) {
#pragma unroll
    for (int r = 0; r < 4; r++) {
      int o = o0 + mi * 16 + l4 * 4 + r;
      Ob[(long)o * NPOS + n] = acc[mi][r] + bias[o] + Rb[(long)o * NPOS + n];
    }
  }
}

// ---------------- final score matrices via MFMA (both directions in one launch) ------
__global__ __launch_bounds__(256) void scores_mfma(
    const float* __restrict__ Mm, float* __restrict__ S0, float* __restrict__ S1, float scale)
{
  __shared__ unsigned short lah[4096], lal[4096];
  __shared__ unsigned short lbh[8192], lbl[8192];
  const int t = threadIdx.x, lane = t & 63, w = t >> 6;
  const int m0 = blockIdx.x * 128, n0 = blockIdx.y * 64;
  const int g = blockIdx.z & 1, dir = blockIdx.z >> 1;
  const long BS2 = 2L * DIM * NPOS;
  const float* Ag = (dir ? (Mm + BS2) : Mm) + (long)g * DIM * NPOS;
  const float* Bg = (dir ? Mm : (Mm + BS2)) + (long)g * DIM * NPOS;
  float* Sg = (dir ? S1 : S0) + (long)g * NPOS * NPOS;
  f32x4 acc[4][2];
#pragma unroll
  for (int i = 0; i < 4; i++)
#pragma unroll
    for (int j = 0; j < 2; j++) acc[i][j] = (f32x4)0.f;

  const int an = t & 63, acq = t >> 6;
  const int bm = t & 127, bkg = t >> 7;
  const int ami = an >> 4, anl = an & 15;
  const int aks = acq >> 1, ahalf = acq & 1;
  const int bni = bm >> 4, bnl = bm & 15;

  for (int cp = 0; cp < 256; cp += 64) {
#pragma unroll
    for (int q = 0; q < 4; q++) {
      unsigned short h[4], l[4];
#pragma unroll
      for (int j = 0; j < 4; j++) {
        float x = Ag[(long)(cp + acq * 16 + q * 4 + j) * NPOS + n0 + an];
        cvt2(x, h[j], l[j]);
      }
      int idx = ((ami * 2 + aks) * 64 + anl + 16 * q) * 8 + ahalf * 4;
      *(u32x2*)&lah[idx] = pack4(h);
      *(u32x2*)&lal[idx] = pack4(l);
    }
#pragma unroll
    for (int q = 0; q < 8; q++) {
      unsigned short h[4], l[4];
#pragma unroll
      for (int j = 0; j < 4; j++) {
        float x = Bg[(long)(cp + bkg * 32 + q * 4 + j) * NPOS + m0 + bm];
        cvt2(x, h[j], l[j]);
      }
      int qm = q & 3, half = (q >> 2) & 1;
      int idx = ((bni * 2 + bkg) * 64 + bnl + 16 * qm) * 8 + half * 4;
      *(u32x2*)&lbh[idx] = pack4(h);
      *(u32x2*)&lbl[idx] = pack4(l);
    }
    __syncthreads();
#pragma unroll
    for (int ks = 0; ks < 2; ks++) {
      u32x4 Ah[4], Al[4], Bh[2], Bl[2];
#pragma unroll
      for (int mi = 0; mi < 4; mi++) {
        Ah[mi] = *(const u32x4*)&lah[((mi * 2 + ks) * 64 + lane) * 8];
        Al[mi] = *(const u32x4*)&lal[((mi * 2 + ks) * 64 + lane) * 8];
      }
#pragma unroll
      for (int ni = 0; ni < 2; ni++) {
        int gg = w * 2 + ni;
        Bh[ni] = *(const u32x4*)&lbh[((gg * 2 + ks) * 64 + lane) * 8];
        Bl[ni] = *(const u32x4*)&lbl[((gg * 2 + ks) * 64 + lane) * 8];
      }
#pragma unroll
      for (int mi = 0; mi < 4; mi++)
#pragma unroll
        for (int ni = 0; ni < 2; ni++) {
          mfma_bf16(acc[mi][ni], Ah[mi], Bh[ni]);
          mfma_bf16(acc[mi][ni], Ah[mi], Bl[ni]);
          mfma_bf16(acc[mi][ni], Al[mi], Bh[ni]);
        }
    }
    __syncthreads();
  }
  MFMA_FENCE();
  const int l15 = lane & 15, l4 = lane >> 4;
#pragma unroll
  for (int mi = 0; mi < 4; mi++)
#pragma unroll
    for (int r = 0; r < 4; r++) {
      int n = n0 + mi * 16 + l4 * 4 + r;
#pragma unroll
      for (int ni = 0; ni < 2; ni++) {
        int m = m0 + (w * 2 + ni) * 16 + l15;
        Sg[(long)n * NPOS + m] = acc[mi][ni][r] * scale;
      }
    }
}

// ---------------- partial flash attention: split over m (z=0: tiles 0-7, z=1: 8-15) -------
// Emits unnormalized O_part and per-column (M, L). ML layout: [split(2)][g(16)][n(1024)].
__global__ __launch_bounds__(256) void flash_part(
    const float* __restrict__ Q, const float* __restrict__ K,
    const float* __restrict__ V, float* __restrict__ Op,
    float* __restrict__ Mp, float* __restrict__ Lp, int cross)
{
  __shared__ unsigned short lqh[4096], lql[4096];
  __shared__ unsigned short lkh[4096], lkl[4096];
  __shared__ unsigned short lvh[4096], lvl[4096];
  const int t = threadIdx.x, lane = t & 63, w = t >> 6;
  const int lin = blockIdx.x + 16 * blockIdx.y;
  const int split = blockIdx.z;
  const int xcd = lin & 7, slot = lin >> 3;
  const int g = xcd * 2 + (slot >> 4);
  const int n0 = (slot & 15) * 64;
  const int s = g >> 3, b = (g >> 2) & 1, h = g & 3;
  const int sba = s * 2 + b;
  const int sbb = (cross ? (1 - s) : s) * 2 + b;
  const float* Qg = Q + ((long)sba * DIM + h) * NPOS;
  const float* Kg = K + ((long)sbb * DIM + h) * NPOS;
  const float* Vg = V + ((long)sbb * DIM + h) * NPOS;
  float*       Og = Op + (long)split * 1048576 + ((long)sba * DIM + h) * NPOS;

  // stage Q once (scaled): B-operand layout
  {
    const int n = t & 63;
#pragma unroll
    for (int qq = 0; qq < 4; qq++) {
      int dq = (t >> 6) + qq * 4;
      unsigned short hh[4], ll[4];
#pragma unroll
      for (int j = 0; j < 4; j++) {
        float x = Qg[(long)(4 * (dq * 4 + j)) * NPOS + n0 + n] * 0.125f;
        cvt2(x, hh[j], ll[j]);
      }
      int idx = (((n >> 4) * 2 + (dq >> 3)) * 64 + (n & 15) + 16 * (dq & 3)) * 8 + ((dq >> 2) & 1) * 4;
      *(u32x2*)&lqh[idx] = pack4(hh);
      *(u32x2*)&lql[idx] = pack4(ll);
    }
  }

  float M = -1e30f, L = 0.f;
  f32x4 acc_o[4];
#pragma unroll
  for (int i = 0; i < 4; i++) acc_o[i] = (f32x4)0.f;

  // T14 prefetch: next m-tile's K (16 scalars) + V (4 float4) in registers.
  const int km = t & 63;
  const int vmq = t & 15;
  float pk[16];
  float4 pv4[4];
  auto loadKV = [&](int m0) {
#pragma unroll
    for (int qq = 0; qq < 4; qq++) {
      int dq = (t >> 6) + qq * 4;
#pragma unroll
      for (int j = 0; j < 4; j++)
        pk[qq * 4 + j] = Kg[(long)(4 * (dq * 4 + j)) * NPOS + m0 + km];
    }
#pragma unroll
    for (int pp = 0; pp < 4; pp++) {
      int d = (t >> 4) + pp * 16;
      pv4[pp] = *(const float4*)(Vg + (long)(4 * d) * NPOS + m0 + vmq * 4);
    }
  };

  const int mbase = split * 8;
  loadKV(mbase * 64);
  for (int mt = 0; mt < 8; mt++) {
    __syncthreads();
#pragma unroll
    for (int qq = 0; qq < 4; qq++) {
      int dq = (t >> 6) + qq * 4;
      unsigned short hh[4], ll[4];
#pragma unroll
      for (int j = 0; j < 4; j++) cvt2(pk[qq * 4 + j], hh[j], ll[j]);
      int idx = (((km >> 4) * 2 + (dq >> 3)) * 64 + (km & 15) + 16 * (dq & 3)) * 8 + ((dq >> 2) & 1) * 4;
      *(u32x2*)&lkh[idx] = pack4(hh);
      *(u32x2*)&lkl[idx] = pack4(ll);
    }
#pragma unroll
    for (int pp = 0; pp < 4; pp++) {
      int d = (t >> 4) + pp * 16;
      unsigned short hh[4], ll[4];
      cvt2(pv4[pp].x, hh[0], ll[0]); cvt2(pv4[pp].y, hh[1], ll[1]);
      cvt2(pv4[pp].z, hh[2], ll[2]); cvt2(pv4[pp].w, hh[3], ll[3]);
      int idx = (((d >> 4) * 2 + (vmq >> 3)) * 64 + (d & 15) + 16 * (vmq & 3)) * 8 + ((vmq >> 2) & 1) * 4;
      *(u32x2*)&lvh[idx] = pack4(hh);
      *(u32x2*)&lvl[idx] = pack4(ll);
    }
    __syncthreads();
    if (mt + 1 < 8) loadKV((mbase + mt + 1) * 64);

    // QK^T
    f32x4 s_[4];
#pragma unroll
    for (int ms = 0; ms < 4; ms++) s_[ms] = (f32x4)0.f;
#pragma unroll
    for (int ks = 0; ks < 2; ks++) {
      u32x4 Bh = *(const u32x4*)&lqh[((w * 2 + ks) * 64 + lane) * 8];
      u32x4 Bl = *(const u32x4*)&lql[((w * 2 + ks) * 64 + lane) * 8];
#pragma unroll
      for (int ms = 0; ms < 4; ms++) {
        u32x4 Ah = *(const u32x4*)&lkh[((ms * 2 + ks) * 64 + lane) * 8];
        u32x4 Al = *(const u32x4*)&lkl[((ms * 2 + ks) * 64 + lane) * 8];
        mfma_bf16_hz(s_[ms], Ah, Bh);
        mfma_bf16_hz(s_[ms], Ah, Bl);
        mfma_bf16_hz(s_[ms], Al, Bh);
      }
    }
    MFMA_FENCE();

    // online softmax in registers (lane: n = 16w+(lane&15); 16 m-values)
    float p[4][4];
    float tm = -1e30f;
#pragma unroll
    for (int ms = 0; ms < 4; ms++)
#pragma unroll
      for (int r = 0; r < 4; r++) tm = fmaxf(tm, s_[ms][r]);
    tm = fmaxf(tm, __shfl_xor(tm, 16));
    tm = fmaxf(tm, __shfl_xor(tm, 32));
    float nm = fmaxf(M, tm);
    float fi = __expf(M - nm);
    float rs = 0.f;
#pragma unroll
    for (int ms = 0; ms < 4; ms++)
#pragma unroll
      for (int r = 0; r < 4; r++) {
        float pv = __expf(s_[ms][r] - nm);
        p[ms][r] = pv; rs += pv;
      }
    rs += __shfl_xor(rs, 16);
    rs += __shfl_xor(rs, 32);
    L = L * fi + rs;
    M = nm;

    // pack P into PV B-operands (D-frag is B-layout at same lane)
    u32x4 Bp_h[2], Bp_l[2];
#pragma unroll
    for (int ks = 0; ks < 2; ks++) {
      unsigned short h0[4], l0[4], h1[4], l1[4];
#pragma unroll
      for (int r = 0; r < 4; r++) {
        cvt2(p[2 * ks][r], h0[r], l0[r]);
        cvt2(p[2 * ks + 1][r], h1[r], l1[r]);
      }
      u32x2 a = pack4(h0), bq = pack4(h1);
      Bp_h[ks].x = a.x; Bp_h[ks].y = a.y; Bp_h[ks].z = bq.x; Bp_h[ks].w = bq.y;
      u32x2 c = pack4(l0), dq = pack4(l1);
      Bp_l[ks].x = c.x; Bp_l[ks].y = c.y; Bp_l[ks].z = dq.x; Bp_l[ks].w = dq.y;
    }
#pragma unroll
    for (int ds = 0; ds < 4; ds++)
#pragma unroll
      for (int r = 0; r < 4; r++) acc_o[ds][r] *= fi;

    // PV: O^T[d][n] += V^T · P
#pragma unroll
    for (int ks = 0; ks < 2; ks++)
#pragma unroll
      for (int ds = 0; ds < 4; ds++) {
        u32x4 Ah = *(const u32x4*)&lvh[((ds * 2 + ks) * 64 + lane) * 8];
        u32x4 Al = *(const u32x4*)&lvl[((ds * 2 + ks) * 64 + lane) * 8];
        mfma_bf16_hz(acc_o[ds], Ah, Bp_h[ks]);
        mfma_bf16_hz(acc_o[ds], Ah, Bp_l[ks]);
        mfma_bf16_hz(acc_o[ds], Al, Bp_h[ks]);
      }
    MFMA_FENCE();
  }

  MFMA_FENCE();
  const int nn = n0 + (w << 4) + (lane & 15);
  // unnormalized partial output + per-column stats
#pragma unroll
  for (int ds = 0; ds < 4; ds++)
#pragma unroll
    for (int r = 0; r < 4; r++) {
      int d = ds * 16 + (lane >> 4) * 4 + r;
      Og[(long)(4 * d) * NPOS + nn] = acc_o[ds][r];
    }
  if ((lane >> 4) == 0) {
    Mp[(long)split * 16384 + g * 1024 + nn] = M;
    Lp[(long)split * 16384 + g * 1024 + nn] = L;
  }
}

// ---------------- fold Wm into W1: Wcat = [W1_l | W1_u*Wm], bcat = B1 + W1_u*Bm -------------
__global__ __launch_bounds__(256) void foldW1(
    const float* __restrict__ w1g, const float* __restrict__ mwg,
    const float* __restrict__ b1g, const float* __restrict__ mbg,
    float* __restrict__ Wcat, float* __restrict__ bcat)
{
  const int z = blockIdx.z;
  const float* W1 = w1g + (long)z * 262144;
  const float* Wm = mwg + (long)z * 65536;
  float* out = Wcat + (long)z * 262144;
  const int o0 = blockIdx.y * 64;
  const int t = threadIdx.x;
  if (blockIdx.x >= 4) {
    const int c0 = (int)(blockIdx.x - 4) * 64;
    const int row = t >> 2, cb = (t & 3) * 16;
#pragma unroll
    for (int q = 0; q < 4; q++) {
      *(float4*)(out + (long)(o0 + row) * 512 + c0 + cb + 4 * q) =
          *(const float4*)(W1 + (long)(o0 + row) * 512 + c0 + cb + 4 * q);
    }
    if (blockIdx.x == 4 && t < 64) {
      int o = o0 + t;
      float acc = b1g[z * 512 + o];
      const float* wr = W1 + (long)o * 512 + 256;
      const float* bm = mbg + z * 256;
      for (int j = 0; j < 256; j++) acc += wr[j] * bm[j];
      bcat[z * 512 + o] = acc;
    }
    return;
  }
  __shared__ float As[16][64], Xs[16][64];
  const int c0 = blockIdx.x * 64;
  const int lr = t >> 2, lc = (t & 3) << 2;
  const int xr = t >> 4, xc = (t & 15) << 2;
  const int ty = t >> 4, tx = t & 15;
  float acc[4][4] = {};
  for (int j0 = 0; j0 < 256; j0 += 16) {
    float4 av = *(const float4*)(W1 + (long)(o0 + lr) * 512 + 256 + j0 + lc);
    As[lc + 0][lr] = av.x; As[lc + 1][lr] = av.y; As[lc + 2][lr] = av.z; As[lc + 3][lr] = av.w;
    *(float4*)&Xs[xr][xc] = *(const float4*)(Wm + (long)(j0 + xr) * 256 + c0 + xc);
    __syncthreads();
#pragma unroll
    for (int kk = 0; kk < 16; kk++) {
      float4 a4 = *(const float4*)&As[kk][ty << 2];
      float4 b4 = *(const float4*)&Xs[kk][tx << 2];
      acc[0][0] += a4.x * b4.x; acc[0][1] += a4.x * b4.y; acc[0][2] += a4.x * b4.z; acc[0][3] += a4.x * b4.w;
      acc[1][0] += a4.y * b4.x; acc[1][1] += a4.y * b4.y; acc[1][2] += a4.y * b4.z; acc[1][3] += a4.y * b4.w;
      acc[2][0] += a4.z * b4.x; acc[2][1] += a4.z * b4.y; acc[2][2] += a4.z * b4.z; acc[2][3] += a4.z * b4.w;
      acc[3][0] += a4.w * b4.x; acc[3][1] += a4.w * b4.y; acc[3][2] += a4.w * b4.z; acc[3][3] += a4.w * b4.w;
    }
    __syncthreads();
  }
#pragma unroll
  for (int i = 0; i < 4; i++) {
    float4 v = make_float4(acc[i][0], acc[i][1], acc[i][2], acc[i][3]);
    *(float4*)(out + (long)(o0 + (ty << 2) + i) * 512 + 256 + c0 + (tx << 2)) = v;
  }
}

// ---------------- Sinkhorn half-iteration ----------------
__global__ __launch_bounds__(256) void sinkK(const float* __restrict__ S,
                                             const float* __restrict__ vin,
                                             float* __restrict__ uout, float norm)
{
  const int r = blockIdx.x * 4 + (threadIdx.x >> 6);
  const int lane = threadIdx.x & 63;
  const int b = r >> 10;
  const float* row = S + (long)r * NPOS;
  const float* vv = vin + (b << 10);
  float vals[16]; float mx = -1e30f;
#pragma unroll
  for (int i = 0; i < 16; i++) { vals[i] = row[lane + i * 64] + vv[lane + i * 64]; mx = fmaxf(mx, vals[i]); }
  mx = wredmax(mx);
  float s = 0.f;
#pragma unroll
  for (int i = 0; i < 16; i++) s += __expf(vals[i] - mx);
  s = wredsum(s);
  if (lane == 0) uout[r] = norm - (mx + __logf(s));
}

// ---------------- Z = sc + u + v - norm ----------------
__global__ __launch_bounds__(256) void finZ(float* __restrict__ Z, const float* __restrict__ u,
                                            const float* __restrict__ v, float norm)
{
  long i = (long)blockIdx.x * 256 + threadIdx.x;
  float4 z = ((float4*)Z)[i];
  long e = i << 2;
  int b = (int)(e >> 20); int n = (int)((e >> 10) & 1023); int m = (int)(e & 1023);
  float add = u[(b << 10) + n] - norm;
  const float* vb = v + (b << 10) + m;
  z.x += add + vb[0]; z.y += add + vb[1]; z.z += add + vb[2]; z.w += add + vb[3];
  ((float4*)Z)[i] = z;
}

// ---------------- keypoint encoder (both streams in one launch) ----------
template<int O, int I>
__device__ __forceinline__ void stage_mm(const float* __restrict__ W, const float* __restrict__ bias,
                                         const float* xin, float* xout, int g, int p)
{
  for (int o = g; o < O; o += 4) {
    float acc = bias[o];
    const float* wr = W + o * I;
    for (int i = 0; i < I; i++) acc += wr[i] * xin[i * 64 + p];
    xout[o * 64 + p] = acc;
  }
  __syncthreads();
}
template<int C>
__device__ __forceinline__ void stage_ln(float* x, const float* __restrict__ ga,
                                         const float* __restrict__ be, float* red, int g, int p)
{
  float s = 0.f, s2 = 0.f;
  for (int c = g; c < C; c += 4) { float v = x[c * 64 + p]; s += v; s2 += v * v; }
  red[g * 64 + p] = s; red[(4 + g) * 64 + p] = s2;
  __syncthreads();
  float S  = red[p] + red[64 + p] + red[128 + p] + red[192 + p];
  float S2 = red[256 + p] + red[320 + p] + red[384 + p] + red[448 + p];
  float mean = S / (float)C;
  float var  = (S2 - (float)C * mean * mean) / (float)(C - 1);
  float inv  = 1.f / (sqrtf(fmaxf(var, 0.f)) + 1e-6f);
  __syncthreads();
  for (int c = g; c < C; c += 4) {
    float v = (x[c * 64 + p] - mean) * inv * ga[c] + be[c];
    x[c * 64 + p] = fmaxf(v, 0.f);
  }
  __syncthreads();
}

__global__ __launch_bounds__(256) void kencK(
    const float* __restrict__ kpts0, const float* __restrict__ scr0, const float* __restrict__ desc0,
    const float* __restrict__ kpts1, const float* __restrict__ scr1, const float* __restrict__ desc1,
    const float* __restrict__ w0, const float* __restrict__ b0, const float* __restrict__ g0, const float* __restrict__ be0,
    const float* __restrict__ w1, const float* __restrict__ b1, const float* __restrict__ g1, const float* __restrict__ be1,
    const float* __restrict__ w2, const float* __restrict__ b2, const float* __restrict__ g2, const float* __restrict__ be2,
    const float* __restrict__ w3, const float* __restrict__ b3,
    float* __restrict__ dout)
{
  __shared__ float a0[3 * 64], a1[32 * 64], a2[64 * 64], a3[128 * 64], red[8 * 64];
  const int t = threadIdx.x, p = t & 63, g = t >> 6;
  const int strm = blockIdx.x >> 5;
  const int blk = blockIdx.x & 31;
  const float* kpts = strm ? kpts1 : kpts0;
  const float* scr  = strm ? scr1  : scr0;
  const float* desc = strm ? desc1 : desc0;
  float* dst = dout + (long)strm * 2 * DIM * NPOS;
  const int b = blk >> 4, n0 = (blk & 15) << 6;
  if (g == 0)      a0[p]        = kpts[((b << 10) + n0 + p) * 2];
  else if (g == 1) a0[64 + p]   = kpts[((b << 10) + n0 + p) * 2 + 1];
  else if (g == 2) a0[128 + p]  = scr[(b << 10) + n0 + p];
  __syncthreads();
  stage_mm<32, 3>(w0, b0, a0, a1, g, p);   stage_ln<32>(a1, g0, be0, red, g, p);
  stage_mm<64, 32>(w1, b1, a1, a2, g, p);  stage_ln<64>(a2, g1, be1, red, g, p);
  stage_mm<128, 64>(w2, b2, a2, a3, g, p); stage_ln<128>(a3, g2, be2, red, g, p);
  for (int o = g; o < 256; o += 4) {
    float acc = b3[o];
    const float* wr = w3 + o * 128;
    for (int i = 0; i < 128; i++) acc += wr[i] * a3[i * 64 + p];
    long idx = ((long)(b * 256 + o) << 10) + n0 + p;
    dst[idx] = desc[idx] + acc;
  }
}

// =====================================================================================
extern "C" void kernel_launch(void* const* d_in, const int* in_sizes, int n_in,
                              void* d_out, int out_size, void* d_ws, size_t ws_size,
                              hipStream_t stream)
{
  (void)in_sizes; (void)n_in; (void)out_size; (void)ws_size;
  const float* desc0   = (const float*)d_in[0];
  const float* desc1   = (const float*)d_in[1];
  const float* kpts0   = (const float*)d_in[2];
  const float* kpts1   = (const float*)d_in[3];
  const float* scores0 = (const float*)d_in[4];
  const float* scores1 = (const float*)d_in[5];
  const float* kw0 = (const float*)d_in[6],  *kb0 = (const float*)d_in[7],
             * kg0 = (const float*)d_in[8],  *kbe0 = (const float*)d_in[9];
  const float* kw1 = (const float*)d_in[10], *kb1 = (const float*)d_in[11],
             * kg1 = (const float*)d_in[12], *kbe1 = (const float*)d_in[13];
  const float* kw2 = (const float*)d_in[14], *kb2 = (const float*)d_in[15],
             * kg2 = (const float*)d_in[16], *kbe2 = (const float*)d_in[17];
  const float* kw3 = (const float*)d_in[18], *kb3 = (const float*)d_in[19];
  const float* qw = (const float*)d_in[20], *qbi = (const float*)d_in[21];
  const float* kw = (const float*)d_in[22], *kbi = (const float*)d_in[23];
  const float* vw = (const float*)d_in[24], *vbi = (const float*)d_in[25];
  const float* mw = (const float*)d_in[26], *mbi = (const float*)d_in[27];
  const float* w1g = (const float*)d_in[28], *b1g = (const float*)d_in[29];
  const float* g1g = (const float*)d_in[30], *be1g = (const float*)d_in[31];
  const float* w2g = (const float*)d_in[32], *b2g = (const float*)d_in[33];
  const float* fw = (const float*)d_in[34], *fb = (const float*)d_in[35];

  float* ws = (float*)d_ws;
  const long M1 = 1048576;
  float* d_a  = ws;
  float* d_b  = ws + 1 * M1;
  float* qb   = ws + 2 * M1;
  float* kb   = ws + 3 * M1;
  float* vb   = ws + 4 * M1;
  float* msgb = ws + 5 * M1;            // final-phase mm buffer only
  float* Opart = ws + 6 * M1;           // 2 x 1M partial flash outputs
  float* Pb   = ws + 8 * M1;
  float* t1   = Pb;                     // [4][512][1024], 2M (raw W1 output)
  float* Wcat = ws + 10 * M1;           // 18*512*512 = 4.5M
  float* bcat = ws + 15 * M1;           // 18*512
  float* psum = ws + 15 * M1 + 16384;   // [8][4][1024]
  float* psq  = psum + 32768;           // [8][4][1024]
  float* Mpart = psq + 32768;           // [2][16][1024]
  float* Lpart = Mpart + 32768;         // [2][16][1024]
  float* uu   = ws + 16 * M1;
  float* vv   = uu + 2048;
  float* scT  = qb;                     // alias, final phase
  float* mmb  = msgb;                   // alias, final phase

  foldW1<<<dim3(8, 8, 18), 256, 0, stream>>>(w1g, mw, b1g, mbi, Wcat, bcat);

  kencK<<<64, 256, 0, stream>>>(kpts0, scores0, desc0, kpts1, scores1, desc1,
      kw0, kb0, kg0, kbe0, kw1, kb1, kg1, kbe1, kw2, kb2, kg2, kbe2, kw3, kb3, d_a);

  float* dc = d_a; float* dn = d_b;
  const long BS1 = (long)DIM * NPOS;
  for (int i = 0; i < NLAYER; i++) {
    int cross = i & 1;
    const float* Wq = qw + (long)i * 65536;  const float* Bq = qbi + (long)i * 256;
    const float* Wk = kw + (long)i * 65536;  const float* Bk = kbi + (long)i * 256;
    const float* Wv = vw + (long)i * 65536;  const float* Bv = vbi + (long)i * 256;
    const float* W1 = Wcat + (long)i * 262144; const float* B1 = bcat + (long)i * 512;
    const float* G1 = g1g + (long)i * 512;    const float* BE1 = be1g + (long)i * 512;
    const float* W2 = w2g + (long)i * 131072; const float* B2 = b2g + (long)i * 256;

    gemm_qkv_mfma<<<dim3(16, 4, 12), 256, 0, stream>>>(Wq, Bq, Wk, Bk, Wv, Bv, dc, qb);
    flash_part<<<dim3(16, 16, 2), 256, 0, stream>>>(qb, kb, vb, Opart, Mpart, Lpart, cross);
    gemm_w1s_mfma<<<dim3(16, 8, 4), 256, 0, stream>>>(W1, B1, dc, Opart, Mpart, Lpart,
                                                      t1, psum, psq);
    gemm_w2ln_mfma<<<dim3(16, 4, 4), 256, 0, stream>>>(W2, B2, t1, G1, BE1, psum, psq, dn, dc);
    float* tmp = dc; dc = dn; dn = tmp;
  }

  gemm_mfma<false, false><<<dim3(16, 4, 4), 256, 0, stream>>>(
      fw, fb, dc, nullptr, mmb, nullptr, 256, BS1, 0, BS1, 0);
  float* scf = (float*)d_out;
  scores_mfma<<<dim3(8, 16, 4), 256, 0, stream>>>(mmb, scf, scT, 0.0625f);

  hipMemsetAsync(vv, 0, 2048 * sizeof(float), stream);
  for (int it = 0; it < 100; it++) {
    sinkK<<<512, 256, 0, stream>>>(scf, vv, uu, NORMC);
    sinkK<<<512, 256, 0, stream>>>(scT, uu, vv, NORMC);
  }
  finZ<<<2048, 256, 0, stream>>>(scf, uu, vv, NORMC);
}